// Round 5
// baseline (433.057 us; speedup 1.0000x reference)
//
#include <hip/hip_runtime.h>
#include <hip/hip_fp16.h>

// Problem constants (B=4, C=128, H=W=64 -> HW=4096)
#define BATCH 4
#define CCH   128
#define HWSZ  4096

typedef _Float16 half8 __attribute__((ext_vector_type(8)));
typedef short short8 __attribute__((ext_vector_type(8)));
typedef float floatx4 __attribute__((ext_vector_type(4)));
typedef unsigned short ushort4v __attribute__((ext_vector_type(4)));
typedef unsigned int uint2v __attribute__((ext_vector_type(2)));

__device__ __forceinline__ unsigned short f2bf(float f) {
    union { float f; unsigned u; } v; v.f = f;
    return (unsigned short)((v.u + 0x7fffu + ((v.u >> 16) & 1u)) >> 16);
}

// pack 2 f32 -> 2 bf16 in one dword (low = a, high = b)
__device__ __forceinline__ unsigned cvtpk(float a, float b) {
    unsigned r;
    asm("v_cvt_pk_bf16_f32 %0, %1, %2" : "=v"(r) : "v"(a), "v"(b));
    return r;
}

// prep: x fp32 [B][C][HW] -> xt fp16 [B][HW][C] (transposed), xf bf16 [B][C][HW]
__global__ __launch_bounds__(256) void prep_kernel(
    const float* __restrict__ x1, const float* __restrict__ x2,
    _Float16* __restrict__ x1t, _Float16* __restrict__ x2t,
    unsigned short* __restrict__ x1f, unsigned short* __restrict__ x2f)
{
    __shared__ float lds[32][33];
    int idx = blockIdx.x;            // 0..4095
    int which = idx >> 11;           // 0: x1, 1: x2
    int r = idx & 2047;
    int cb  = r & 3;                 // C/32  = 4
    int hwb = (r >> 2) & 127;        // HW/32 = 128
    int b   = r >> 9;                // 4 batches
    const float* x = which ? x2 : x1;
    _Float16* xt = which ? x2t : x1t;
    unsigned short* xf = which ? x2f : x1f;
    int tid = threadIdx.x;
    int tc = tid >> 5, th = tid & 31;
    #pragma unroll
    for (int k = 0; k < 4; ++k) {
        int cl = tc + 8 * k;
        int c = cb * 32 + cl, hw = hwb * 32 + th;
        float v = x[((size_t)b * CCH + c) * HWSZ + hw];
        lds[cl][th] = v;
        xf[((size_t)b * CCH + c) * HWSZ + hw] = f2bf(v);
    }
    __syncthreads();
    #pragma unroll
    for (int k = 0; k < 4; ++k) {
        int hl = tc + 8 * k;
        xt[((size_t)b * HWSZ + hwb * 32 + hl) * CCH + cb * 32 + th] =
            (_Float16)lds[th][hl];
    }
}

// raw barrier: LDS drain + barrier, no vmcnt drain; sched fences keep the
// staging loads pinned on their issue side.
#define FBAR() do { __builtin_amdgcn_sched_barrier(0); \
    asm volatile("s_waitcnt lgkmcnt(0)" ::: "memory"); \
    __builtin_amdgcn_s_barrier(); \
    __builtin_amdgcn_sched_barrier(0); } while (0)

// Fused partial pass, col-tile = 128, 16 waves, LDS-staged loop streams.
// For col-slice `slice` (128 cols) and loop-part `part` (4096/P rows):
//   A[row,col] = sum_c loopT[row][c]*blockT[col][c]   (fp16 MFMA, K=128)
//   E = exp(A) (bf16 -> swizzled LDS)
//   accP[c][col] += sum_row loopF[c][row]*E[row][col] (bf16 MFMA)
//   colsum[col]  += sum_row E
// Per chunk (64 rows): stage af (xt rows, 16KB) + pa (xf cols, 16KB) into
// LDS via reg-staging with swizzled LDS writes. Single-buffered AF/PA/E
// with 2 barriers/chunk:
//   issue loads(t+1); gram reads AF(t); E-write; B1; PV reads PA(t)+E;
//   AF<-t+1 (AF readers all pre-B1); B2; PA<-t+1 (PA readers all pre-B2).
// Grid = 128*P (P parts) -> 2 blocks/CU at P=4 to fill barrier stalls.
__global__ __launch_bounds__(1024, 8) void fused_part(
    const _Float16* __restrict__ loopT,
    const _Float16* __restrict__ blockT,
    const unsigned short* __restrict__ loopF,
    float* __restrict__ accPo,    // [P][B][32][128 c][128 col]
    float* __restrict__ cso,      // [P][B][32][128]
    int P)
{
    __shared__ unsigned short AF[8192];   // 64 rows x 128 c fp16, swizzled 16B units
    __shared__ unsigned short PA[8192];   // 128 c x 64 rows bf16, swizzled
    __shared__ unsigned short EB[8192];   // 128 cols x 64 rows bf16, swizzled

    int bid = blockIdx.x;
    int xcd = bid & 7, grp = bid >> 3;    // grp 0..16P-1
    int b = xcd >> 1;                     // 2 XCDs per batch (L2 locality)
    int slice = (grp & 15) + 16 * (xcd & 1);   // 0..31 (128 cols each)
    int part = grp >> 4;                  // 0..P-1
    int tid = threadIdx.x;
    int wave = tid >> 6, lane = tid & 63;
    int l16 = lane & 15, lg = lane >> 4;
    int nt = wave & 3, mh = wave >> 2;    // gram: row-tile nt, col-32-group mh
    int swz = l16 & 7;
    int NC = 64 / P;
    int ch0 = part * NC, ch1 = ch0 + NC;

    const _Float16* lT = loopT + (size_t)b * HWSZ * CCH;
    const _Float16* bT = blockT + (size_t)b * HWSZ * CCH;
    const unsigned short* lF = loopF + (size_t)b * CCH * HWSZ;

    // hoist gram B frags: col = slice*128 + mh*32 + tt*16 + l16, K=128
    half8 bfrag[2][4];
    #pragma unroll
    for (int tt = 0; tt < 2; ++tt)
        #pragma unroll
        for (int ks = 0; ks < 4; ++ks)
            bfrag[tt][ks] = *(const half8*)&bT[
                (size_t)(slice * 128 + mh * 32 + tt * 16 + l16) * CCH + ks * 32 + lg * 8];

    // staging addressing: thread owns one 16B unit of each tile.
    // AF: unit u: row=u>>4 (64), s=u&15. LDS unit = row*16 + (s ^ (row&7)).
    int arow = tid >> 4, as_ = tid & 15;
    const _Float16* afsrc = lT + (size_t)arow * CCH + as_ * 8;
    int afw = (arow * 16 + (as_ ^ (arow & 7))) * 8;      // ushort index
    // PA: unit u: c=u>>3 (128), s=u&7
    int pc = tid >> 3, ps = tid & 7;
    const unsigned short* pasrc = lF + (size_t)pc * HWSZ + ps * 8;
    int paw = (pc * 8 + (ps ^ (pc & 7))) * 8;            // ushort index

    float csum0 = 0.f, csum1 = 0.f;
    floatx4 accP[2][2];
    #pragma unroll
    for (int ci = 0; ci < 2; ++ci)
        #pragma unroll
        for (int cj = 0; cj < 2; ++cj) accP[ci][cj] = (floatx4){0.f, 0.f, 0.f, 0.f};

    // E-tile addresses (loop-invariant)
    int wo0 = (mh * 32 + l16) * 64 + (((nt * 2 + (lg >> 1)) ^ swz) << 3) + ((lg & 1) << 2);
    int wo1 = wo0 + 16 * 64;

    // prologue: stage chunk ch0
    {
        floatx4 ga = *(const floatx4*)(afsrc + (size_t)ch0 * 64 * CCH);
        floatx4 gp = *(const floatx4*)(pasrc + ch0 * 64);
        *(floatx4*)&AF[afw] = ga;
        *(floatx4*)&PA[paw] = gp;
    }
    __syncthreads();

    for (int t = ch0; t < ch1; ++t) {
        int t1 = (t + 1 < ch1) ? t + 1 : t;
        // issue next-chunk staging loads (ride over both barriers)
        floatx4 ga = *(const floatx4*)(afsrc + (size_t)t1 * 64 * CCH);
        floatx4 gp = *(const floatx4*)(pasrc + t1 * 64);
        // ---- gram: rows nt*16.., cols mh*32 + {0,16} + l16, K=128 (fp16)
        half8 afr[4];
        #pragma unroll
        for (int ks = 0; ks < 4; ++ks)
            afr[ks] = *(const half8*)&AF[((nt * 16 + l16) * 16 + ((ks * 4 + lg) ^ swz)) * 8];
        floatx4 accA0 = {0.f, 0.f, 0.f, 0.f}, accA1 = {0.f, 0.f, 0.f, 0.f};
        #pragma unroll
        for (int ks = 0; ks < 4; ++ks) {
            accA0 = __builtin_amdgcn_mfma_f32_16x16x32_f16(afr[ks], bfrag[0][ks], accA0, 0, 0, 0);
            accA1 = __builtin_amdgcn_mfma_f32_16x16x32_f16(afr[ks], bfrag[1][ks], accA1, 0, 0, 0);
        }
        // ---- exp (no max-sub: |A| << 88) + pk-bf16 pack + colsum partials
        float v00 = __expf(accA0[0]), v01 = __expf(accA0[1]);
        float v02 = __expf(accA0[2]), v03 = __expf(accA0[3]);
        float v10 = __expf(accA1[0]), v11 = __expf(accA1[1]);
        float v12 = __expf(accA1[2]), v13 = __expf(accA1[3]);
        csum0 += (v00 + v01) + (v02 + v03);
        csum1 += (v10 + v11) + (v12 + v13);
        uint2v e0 = (uint2v){cvtpk(v00, v01), cvtpk(v02, v03)};
        uint2v e1 = (uint2v){cvtpk(v10, v11), cvtpk(v12, v13)};
        *(uint2v*)&EB[wo0] = e0;
        *(uint2v*)&EB[wo1] = e1;
        FBAR();   // B1: E visible; all AF reads of tile t complete block-wide
        // ---- PV: accP[c-tiles nt*2+ci][col-tiles mh*2+cj], k = 64 rows (bf16)
        #pragma unroll
        for (int kf = 0; kf < 2; ++kf) {
            short8 paf[2], ebf[2];
            #pragma unroll
            for (int ci = 0; ci < 2; ++ci) {
                int c = (nt * 2 + ci) * 16 + l16;
                paf[ci] = *(const short8*)&PA[(c * 8 + ((kf * 4 + lg) ^ swz)) * 8];
            }
            #pragma unroll
            for (int cj = 0; cj < 2; ++cj) {
                int ecol = (mh * 2 + cj) * 16 + l16;
                ebf[cj] = *(const short8*)&EB[ecol * 64 + (((kf * 4 + lg) ^ swz) << 3)];
            }
            #pragma unroll
            for (int ci = 0; ci < 2; ++ci)
                #pragma unroll
                for (int cj = 0; cj < 2; ++cj)
                    accP[ci][cj] = __builtin_amdgcn_mfma_f32_16x16x32_bf16(
                        paf[ci], ebf[cj], accP[ci][cj], 0, 0, 0);
        }
        // ---- stage writes: AF (readers finished at B1), then barrier, then PA
        *(floatx4*)&AF[afw] = ga;
        FBAR();   // B2: PV reads of tile t complete; AF(t+1) visible
        *(floatx4*)&PA[paw] = gp;   // visible at next B1
    }
    __syncthreads();   // final PA write drained before aliasing

    // ---- colsum: deterministic cross-wave reduce (alias scratch onto PA)
    float* cspart = (float*)PA;   // [4][128]
    float v = csum0;
    v += __shfl_xor(v, 16, 64); v += __shfl_xor(v, 32, 64);
    float w = csum1;
    w += __shfl_xor(w, 16, 64); w += __shfl_xor(w, 32, 64);
    if (lane < 16) {
        cspart[nt * 128 + mh * 32 + lane] = v;
        cspart[nt * 128 + mh * 32 + 16 + lane] = w;
    }
    __syncthreads();
    size_t sbase = ((size_t)part * BATCH + b) * 32 + slice;
    if (tid < 128)
        cso[sbase * 128 + tid] = cspart[tid] + cspart[128 + tid] +
                                 cspart[256 + tid] + cspart[384 + tid];

    // ---- store partial accP: c = (nt*2+ci)*16 + lg*4 + rr, col = (mh*2+cj)*16 + l16
    float* po = accPo + sbase * (128 * 128);
    #pragma unroll
    for (int ci = 0; ci < 2; ++ci)
        #pragma unroll
        for (int cj = 0; cj < 2; ++cj)
            #pragma unroll
            for (int rr = 0; rr < 4; ++rr)
                po[(size_t)((nt * 2 + ci) * 16 + lg * 4 + rr) * 128 +
                   (mh * 2 + cj) * 16 + l16] = accP[ci][cj][rr];
}

// combine P partials + epilogue: att = accP/colsum;
// out[col] (+)= cw * sum_c gw[c]*sigmoid(att[c][col])*xe[c][col]
template<int ACCUM>
__global__ __launch_bounds__(256) void combine_kernel(
    const float* __restrict__ accPp, const float* __restrict__ csp,
    const float* __restrict__ xe, const float* __restrict__ gw,
    const float* __restrict__ cwp, float* __restrict__ out, int P)
{
    __shared__ float red[256];
    __shared__ float gws[CCH];
    int b = blockIdx.x >> 5, slice = blockIdx.x & 31;
    int tid = threadIdx.x;
    if (tid < CCH) gws[tid] = gw[tid];
    __syncthreads();
    int col = tid & 127, half = tid >> 7;
    float cs = 0.f;
    for (int p = 0; p < P; ++p)
        cs += csp[(((size_t)p * BATCH + b) * 32 + slice) * 128 + col];
    float inv = 1.f / cs;
    float acc = 0.f;
    for (int ci = 0; ci < 64; ++ci) {
        int c = half * 64 + ci;
        float s = 0.f;
        for (int p = 0; p < P; ++p)
            s += accPp[((((size_t)p * BATCH + b) * 32 + slice) * 128 + c) * 128 + col];
        float att = s * inv;
        float mask = 1.f / (1.f + __expf(-att));
        acc += gws[c] * mask * xe[((size_t)b * CCH + c) * HWSZ + slice * 128 + col];
    }
    red[tid] = acc;
    __syncthreads();
    if (tid < 128) {
        float vv = cwp[0] * (red[tid] + red[tid + 128]);
        size_t o = (size_t)b * HWSZ + slice * 128 + tid;
        if (ACCUM) out[o] += vv; else out[o] = vv;
    }
}

extern "C" void kernel_launch(void* const* d_in, const int* in_sizes, int n_in,
                              void* d_out, int out_size, void* d_ws, size_t ws_size,
                              hipStream_t stream) {
    const float* x1 = (const float*)d_in[0];
    const float* x2 = (const float*)d_in[1];
    const float* gw = (const float*)d_in[2];
    const float* cw = (const float*)d_in[3];
    float* out = (float*)d_out;

    char* ws = (char*)d_ws;
    size_t elems = (size_t)BATCH * CCH * HWSZ;  // 2M
    _Float16* x1t = (_Float16*)ws;
    _Float16* x2t = (_Float16*)(ws + elems * 2);
    unsigned short* x1f = (unsigned short*)(ws + elems * 4);
    unsigned short* x2f = (unsigned short*)(ws + elems * 6);
    char* pbase = ws + elems * 8;               // 16 MB used by prep arrays

    // partials per pass: accP P*B*32*128*128*4 + cs P*B*32*128*4
    auto region = [](int P) {
        return (size_t)P * BATCH * 32 * 128 * 128 * 4 +
               (size_t)P * BATCH * 32 * 128 * 4;
    };
    size_t avail = (ws_size > elems * 8) ? ws_size - elems * 8 : 0;
    int P; bool dual;
    if      (avail >= 2 * region(4)) { P = 4; dual = true;  }
    else if (avail >=     region(4)) { P = 4; dual = false; }
    else if (avail >= 2 * region(2)) { P = 2; dual = true;  }
    else if (avail >=     region(2)) { P = 2; dual = false; }
    else                             { P = 1; dual = false; }

    size_t accPbytes = (size_t)P * BATCH * 32 * 128 * 128 * 4;
    float* accP1 = (float*)pbase;
    float* cs1   = (float*)(pbase + accPbytes);
    float* accP2 = dual ? (float*)(pbase + region(P)) : accP1;
    float* cs2   = dual ? (float*)(pbase + region(P) + accPbytes) : cs1;

    prep_kernel<<<4096, 256, 0, stream>>>(x1, x2, x1t, x2t, x1f, x2f);

    if (dual) {
        // pass1 (out2 over m): loopT=x1t, blockT=x2t, loopF=x1f, xe=x2
        fused_part<<<128 * P, 1024, 0, stream>>>(x1t, x2t, x1f, accP1, cs1, P);
        // pass2 (out1 over n): loopT=x2t, blockT=x1t, loopF=x2f, xe=x1
        fused_part<<<128 * P, 1024, 0, stream>>>(x2t, x1t, x2f, accP2, cs2, P);
        combine_kernel<0><<<BATCH * 32, 256, 0, stream>>>(accP1, cs1, x2, gw, cw, out, P);
        combine_kernel<1><<<BATCH * 32, 256, 0, stream>>>(accP2, cs2, x1, gw, cw, out, P);
    } else {
        fused_part<<<128 * P, 1024, 0, stream>>>(x1t, x2t, x1f, accP1, cs1, P);
        combine_kernel<0><<<BATCH * 32, 256, 0, stream>>>(accP1, cs1, x2, gw, cw, out, P);
        fused_part<<<128 * P, 1024, 0, stream>>>(x2t, x1t, x2f, accP1, cs1, P);
        combine_kernel<1><<<BATCH * 32, 256, 0, stream>>>(accP1, cs1, x1, gw, cw, out, P);
    }
}

// Round 6
// 242.801 us; speedup vs baseline: 1.7836x; 1.7836x over previous
//
#include <hip/hip_runtime.h>
#include <hip/hip_fp16.h>

// Problem constants (B=4, C=128, H=W=64 -> HW=4096)
#define BATCH 4
#define CCH   128
#define HWSZ  4096

typedef _Float16 half8 __attribute__((ext_vector_type(8)));
typedef short short8 __attribute__((ext_vector_type(8)));
typedef float floatx4 __attribute__((ext_vector_type(4)));
typedef unsigned short ushort4v __attribute__((ext_vector_type(4)));
typedef unsigned int uint2v __attribute__((ext_vector_type(2)));

__device__ __forceinline__ unsigned short f2bf(float f) {
    union { float f; unsigned u; } v; v.f = f;
    return (unsigned short)((v.u + 0x7fffu + ((v.u >> 16) & 1u)) >> 16);
}

// pack 2 f32 -> 2 bf16 in one dword (low = a, high = b)
__device__ __forceinline__ unsigned cvtpk(float a, float b) {
    unsigned r;
    asm("v_cvt_pk_bf16_f32 %0, %1, %2" : "=v"(r) : "v"(a), "v"(b));
    return r;
}

// prep: x fp32 [B][C][HW] -> xt fp16 [B][HW][C] (transposed), xf bf16 [B][C][HW]
__global__ __launch_bounds__(256) void prep_kernel(
    const float* __restrict__ x1, const float* __restrict__ x2,
    _Float16* __restrict__ x1t, _Float16* __restrict__ x2t,
    unsigned short* __restrict__ x1f, unsigned short* __restrict__ x2f)
{
    __shared__ float lds[32][33];
    int idx = blockIdx.x;            // 0..4095
    int which = idx >> 11;           // 0: x1, 1: x2
    int r = idx & 2047;
    int cb  = r & 3;                 // C/32  = 4
    int hwb = (r >> 2) & 127;        // HW/32 = 128
    int b   = r >> 9;                // 4 batches
    const float* x = which ? x2 : x1;
    _Float16* xt = which ? x2t : x1t;
    unsigned short* xf = which ? x2f : x1f;
    int tid = threadIdx.x;
    int tc = tid >> 5, th = tid & 31;
    #pragma unroll
    for (int k = 0; k < 4; ++k) {
        int cl = tc + 8 * k;
        int c = cb * 32 + cl, hw = hwb * 32 + th;
        float v = x[((size_t)b * CCH + c) * HWSZ + hw];
        lds[cl][th] = v;
        xf[((size_t)b * CCH + c) * HWSZ + hw] = f2bf(v);
    }
    __syncthreads();
    #pragma unroll
    for (int k = 0; k < 4; ++k) {
        int hl = tc + 8 * k;
        xt[((size_t)b * HWSZ + hwb * 32 + hl) * CCH + cb * 32 + th] =
            (_Float16)lds[th][hl];
    }
}

// raw barrier: LDS drain + barrier, no vmcnt drain; sched fences keep the
// global loads pinned on their issue side.
#define FBAR() do { __builtin_amdgcn_sched_barrier(0); \
    asm volatile("s_waitcnt lgkmcnt(0)" ::: "memory"); \
    __builtin_amdgcn_s_barrier(); \
    __builtin_amdgcn_sched_barrier(0); } while (0)

// Fused partial pass, col-tile = 128, 16 waves. LDS-BW-bound design:
//   - gram A (xt rows) staged in LDS, double-buffered (AF[2])
//   - E tile double-buffered (EB[2])
//   - PV A-operand (xf fragments) read DIRECT FROM GLOBAL: the 4x
//     wave redundancy is served by the per-CU L1 (16KB/chunk stream),
//     removing 80KB/chunk (33%) of LDS traffic vs staging it.
//   - single barrier per chunk (provably race-free with the two
//     double buffers; every buffer's last reader precedes the barrier
//     after which its writer writes).
// For col-slice `slice` (128 cols) and loop-part `part` (4096/P rows):
//   A[row,col] = sum_c loopT[row][c]*blockT[col][c]   (fp16 MFMA, K=128)
//   E = exp(A) (bf16 -> swizzled LDS)
//   accP[c][col] += sum_row loopF[c][row]*E[row][col] (bf16 MFMA)
//   colsum[col]  += sum_row E
__global__ __launch_bounds__(1024, 4) void fused_part(
    const _Float16* __restrict__ loopT,
    const _Float16* __restrict__ blockT,
    const unsigned short* __restrict__ loopF,
    float* __restrict__ accPo,    // [P][B][32][128 c][128 col]
    float* __restrict__ cso,      // [P][B][32][128]
    int P)
{
    __shared__ unsigned short AF[2][8192];   // 64 rows x 128 c fp16, swizzled
    __shared__ unsigned short EB[2][8192];   // 128 cols x 64 rows bf16, swizzled

    int bid = blockIdx.x;
    int xcd = bid & 7, grp = bid >> 3;    // grp 0..16P-1
    int b = xcd >> 1;                     // 2 XCDs per batch (L2 locality)
    int slice = (grp & 15) + 16 * (xcd & 1);   // 0..31 (128 cols each)
    int part = grp >> 4;                  // 0..P-1
    int tid = threadIdx.x;
    int wave = tid >> 6, lane = tid & 63;
    int l16 = lane & 15, lg = lane >> 4;
    int nt = wave & 3, mh = wave >> 2;    // gram: row-tile nt, col-32-group mh
    int swz = l16 & 7;
    int NC = 64 / P;
    int ch0 = part * NC, ch1 = ch0 + NC;

    const _Float16* lT = loopT + (size_t)b * HWSZ * CCH;
    const _Float16* bT = blockT + (size_t)b * HWSZ * CCH;
    const unsigned short* lF = loopF + (size_t)b * CCH * HWSZ;

    // hoist gram B frags: col = slice*128 + mh*32 + tt*16 + l16, K=128
    half8 bfrag[2][4];
    #pragma unroll
    for (int tt = 0; tt < 2; ++tt)
        #pragma unroll
        for (int ks = 0; ks < 4; ++ks)
            bfrag[tt][ks] = *(const half8*)&bT[
                (size_t)(slice * 128 + mh * 32 + tt * 16 + l16) * CCH + ks * 32 + lg * 8];

    // AF staging: thread owns one 16B unit. row=tid>>4 (64), s=tid&15.
    // LDS unit = row*16 + (s ^ (row&7)) -> conflict-free b128 frag reads.
    int arow = tid >> 4, as_ = tid & 15;
    const _Float16* afsrc = lT + (size_t)arow * CCH + as_ * 8;
    int afw = (arow * 16 + (as_ ^ (arow & 7))) * 8;      // ushort index

    // PV A-operand global bases: c = (nt*2+ci)*16 + l16, k-unit = (kf*4+lg)*8
    const unsigned short* pv0 = lF + (size_t)((nt * 2 + 0) * 16 + l16) * HWSZ + lg * 8;
    const unsigned short* pv1 = lF + (size_t)((nt * 2 + 1) * 16 + l16) * HWSZ + lg * 8;

    float csum0 = 0.f, csum1 = 0.f;
    floatx4 accP[2][2];
    #pragma unroll
    for (int ci = 0; ci < 2; ++ci)
        #pragma unroll
        for (int cj = 0; cj < 2; ++cj) accP[ci][cj] = (floatx4){0.f, 0.f, 0.f, 0.f};

    // E-tile addresses (loop-invariant)
    int wo0 = (mh * 32 + l16) * 64 + (((nt * 2 + (lg >> 1)) ^ swz) << 3) + ((lg & 1) << 2);
    int wo1 = wo0 + 16 * 64;

    // prologue: stage chunk ch0 into AF[ch0&1]
    {
        floatx4 ga = *(const floatx4*)(afsrc + (size_t)ch0 * 64 * CCH);
        *(floatx4*)&AF[ch0 & 1][afw] = ga;
    }
    __syncthreads();

    for (int t = ch0; t < ch1; ++t) {
        int t1 = (t + 1 < ch1) ? t + 1 : t;
        // issue ALL global loads at iteration top: af staging for t+1 and
        // PV A-frags for t. Latency hides under gram MFMA + exp (~450 cyc).
        floatx4 ga = *(const floatx4*)(afsrc + (size_t)t1 * 64 * CCH);
        short8 paf00 = *(const short8*)(pv0 + t * 64);
        short8 paf01 = *(const short8*)(pv0 + t * 64 + 32);
        short8 paf10 = *(const short8*)(pv1 + t * 64);
        short8 paf11 = *(const short8*)(pv1 + t * 64 + 32);
        // ---- gram: rows nt*16.., cols mh*32 + {0,16} + l16, K=128 (fp16)
        half8 afr[4];
        #pragma unroll
        for (int ks = 0; ks < 4; ++ks)
            afr[ks] = *(const half8*)&AF[t & 1][
                ((nt * 16 + l16) * 16 + ((ks * 4 + lg) ^ swz)) * 8];
        floatx4 accA0 = {0.f, 0.f, 0.f, 0.f}, accA1 = {0.f, 0.f, 0.f, 0.f};
        #pragma unroll
        for (int ks = 0; ks < 4; ++ks) {
            accA0 = __builtin_amdgcn_mfma_f32_16x16x32_f16(afr[ks], bfrag[0][ks], accA0, 0, 0, 0);
            accA1 = __builtin_amdgcn_mfma_f32_16x16x32_f16(afr[ks], bfrag[1][ks], accA1, 0, 0, 0);
        }
        // ---- exp (no max-sub: |A| << 88) + pk-bf16 pack + colsum partials
        float v00 = __expf(accA0[0]), v01 = __expf(accA0[1]);
        float v02 = __expf(accA0[2]), v03 = __expf(accA0[3]);
        float v10 = __expf(accA1[0]), v11 = __expf(accA1[1]);
        float v12 = __expf(accA1[2]), v13 = __expf(accA1[3]);
        csum0 += (v00 + v01) + (v02 + v03);
        csum1 += (v10 + v11) + (v12 + v13);
        uint2v e0 = (uint2v){cvtpk(v00, v01), cvtpk(v02, v03)};
        uint2v e1 = (uint2v){cvtpk(v10, v11), cvtpk(v12, v13)};
        *(uint2v*)&EB[t & 1][wo0] = e0;
        *(uint2v*)&EB[t & 1][wo1] = e1;
        // AF(t+1): all gram reads of AF[t&1] happened above; writing the
        // OTHER buffer. Visible to everyone after FBAR.
        *(floatx4*)&AF[(t + 1) & 1][afw] = ga;
        FBAR();   // single barrier per chunk
        // ---- PV: accP[c-tiles nt*2+ci][col-tiles mh*2+cj], k = 64 rows (bf16)
        #pragma unroll
        for (int kf = 0; kf < 2; ++kf) {
            short8 ebf[2];
            #pragma unroll
            for (int cj = 0; cj < 2; ++cj) {
                int ecol = (mh * 2 + cj) * 16 + l16;
                ebf[cj] = *(const short8*)&EB[t & 1][
                    ecol * 64 + (((kf * 4 + lg) ^ swz) << 3)];
            }
            short8 pa0 = kf ? paf01 : paf00;
            short8 pa1 = kf ? paf11 : paf10;
            #pragma unroll
            for (int cj = 0; cj < 2; ++cj) {
                accP[0][cj] = __builtin_amdgcn_mfma_f32_16x16x32_bf16(pa0, ebf[cj], accP[0][cj], 0, 0, 0);
                accP[1][cj] = __builtin_amdgcn_mfma_f32_16x16x32_bf16(pa1, ebf[cj], accP[1][cj], 0, 0, 0);
            }
        }
    }
    __syncthreads();   // all EB reads drained before aliasing

    // ---- colsum: deterministic cross-wave reduce (alias scratch onto EB)
    float* cspart = (float*)EB;   // [4][128] floats = 2KB
    float v = csum0;
    v += __shfl_xor(v, 16, 64); v += __shfl_xor(v, 32, 64);
    float w = csum1;
    w += __shfl_xor(w, 16, 64); w += __shfl_xor(w, 32, 64);
    if (lane < 16) {
        cspart[nt * 128 + mh * 32 + lane] = v;
        cspart[nt * 128 + mh * 32 + 16 + lane] = w;
    }
    __syncthreads();
    size_t sbase = ((size_t)part * BATCH + b) * 32 + slice;
    if (tid < 128)
        cso[sbase * 128 + tid] = cspart[tid] + cspart[128 + tid] +
                                 cspart[256 + tid] + cspart[384 + tid];

    // ---- store partial accP: c = (nt*2+ci)*16 + lg*4 + rr, col = (mh*2+cj)*16 + l16
    float* po = accPo + sbase * (128 * 128);
    #pragma unroll
    for (int ci = 0; ci < 2; ++ci)
        #pragma unroll
        for (int cj = 0; cj < 2; ++cj)
            #pragma unroll
            for (int rr = 0; rr < 4; ++rr)
                po[(size_t)((nt * 2 + ci) * 16 + lg * 4 + rr) * 128 +
                   (mh * 2 + cj) * 16 + l16] = accP[ci][cj][rr];
}

// combine P partials + epilogue: att = accP/colsum;
// out[col] (+)= cw * sum_c gw[c]*sigmoid(att[c][col])*xe[c][col]
template<int ACCUM>
__global__ __launch_bounds__(256) void combine_kernel(
    const float* __restrict__ accPp, const float* __restrict__ csp,
    const float* __restrict__ xe, const float* __restrict__ gw,
    const float* __restrict__ cwp, float* __restrict__ out, int P)
{
    __shared__ float red[256];
    __shared__ float gws[CCH];
    int b = blockIdx.x >> 5, slice = blockIdx.x & 31;
    int tid = threadIdx.x;
    if (tid < CCH) gws[tid] = gw[tid];
    __syncthreads();
    int col = tid & 127, half = tid >> 7;
    float cs = 0.f;
    for (int p = 0; p < P; ++p)
        cs += csp[(((size_t)p * BATCH + b) * 32 + slice) * 128 + col];
    float inv = 1.f / cs;
    float acc = 0.f;
    for (int ci = 0; ci < 64; ++ci) {
        int c = half * 64 + ci;
        float s = 0.f;
        for (int p = 0; p < P; ++p)
            s += accPp[((((size_t)p * BATCH + b) * 32 + slice) * 128 + c) * 128 + col];
        float att = s * inv;
        float mask = 1.f / (1.f + __expf(-att));
        acc += gws[c] * mask * xe[((size_t)b * CCH + c) * HWSZ + slice * 128 + col];
    }
    red[tid] = acc;
    __syncthreads();
    if (tid < 128) {
        float vv = cwp[0] * (red[tid] + red[tid + 128]);
        size_t o = (size_t)b * HWSZ + slice * 128 + tid;
        if (ACCUM) out[o] += vv; else out[o] = vv;
    }
}

extern "C" void kernel_launch(void* const* d_in, const int* in_sizes, int n_in,
                              void* d_out, int out_size, void* d_ws, size_t ws_size,
                              hipStream_t stream) {
    const float* x1 = (const float*)d_in[0];
    const float* x2 = (const float*)d_in[1];
    const float* gw = (const float*)d_in[2];
    const float* cw = (const float*)d_in[3];
    float* out = (float*)d_out;

    char* ws = (char*)d_ws;
    size_t elems = (size_t)BATCH * CCH * HWSZ;  // 2M
    _Float16* x1t = (_Float16*)ws;
    _Float16* x2t = (_Float16*)(ws + elems * 2);
    unsigned short* x1f = (unsigned short*)(ws + elems * 4);
    unsigned short* x2f = (unsigned short*)(ws + elems * 6);
    char* pbase = ws + elems * 8;               // 16 MB used by prep arrays

    // partials per pass: accP P*B*32*128*128*4 + cs P*B*32*128*4
    auto region = [](int P) {
        return (size_t)P * BATCH * 32 * 128 * 128 * 4 +
               (size_t)P * BATCH * 32 * 128 * 4;
    };
    size_t avail = (ws_size > elems * 8) ? ws_size - elems * 8 : 0;
    int P; bool dual;
    if      (avail >= 2 * region(2)) { P = 2; dual = true;  }
    else if (avail >=     region(2)) { P = 2; dual = false; }
    else                             { P = 1; dual = false; }

    size_t accPbytes = (size_t)P * BATCH * 32 * 128 * 128 * 4;
    float* accP1 = (float*)pbase;
    float* cs1   = (float*)(pbase + accPbytes);
    float* accP2 = dual ? (float*)(pbase + region(P)) : accP1;
    float* cs2   = dual ? (float*)(pbase + region(P) + accPbytes) : cs1;

    prep_kernel<<<4096, 256, 0, stream>>>(x1, x2, x1t, x2t, x1f, x2f);

    if (dual) {
        // pass1 (out2 over m): loopT=x1t, blockT=x2t, loopF=x1f, xe=x2
        fused_part<<<128 * P, 1024, 0, stream>>>(x1t, x2t, x1f, accP1, cs1, P);
        // pass2 (out1 over n): loopT=x2t, blockT=x1t, loopF=x2f, xe=x1
        fused_part<<<128 * P, 1024, 0, stream>>>(x2t, x1t, x2f, accP2, cs2, P);
        combine_kernel<0><<<BATCH * 32, 256, 0, stream>>>(accP1, cs1, x2, gw, cw, out, P);
        combine_kernel<1><<<BATCH * 32, 256, 0, stream>>>(accP2, cs2, x1, gw, cw, out, P);
    } else {
        fused_part<<<128 * P, 1024, 0, stream>>>(x1t, x2t, x1f, accP1, cs1, P);
        combine_kernel<0><<<BATCH * 32, 256, 0, stream>>>(accP1, cs1, x2, gw, cw, out, P);
        fused_part<<<128 * P, 1024, 0, stream>>>(x2t, x1t, x2f, accP1, cs1, P);
        combine_kernel<1><<<BATCH * 32, 256, 0, stream>>>(accP1, cs1, x1, gw, cw, out, P);
    }
}

// Round 7
// 180.255 us; speedup vs baseline: 2.4025x; 1.3470x over previous
//
#include <hip/hip_runtime.h>
#include <hip/hip_fp16.h>

// Problem constants (B=4, C=128, H=W=64 -> HW=4096)
#define BATCH 4
#define CCH   128
#define HWSZ  4096

typedef _Float16 half8 __attribute__((ext_vector_type(8)));
typedef short short8 __attribute__((ext_vector_type(8)));
typedef float floatx4 __attribute__((ext_vector_type(4)));
typedef unsigned short ushort4v __attribute__((ext_vector_type(4)));
typedef unsigned int uint2v __attribute__((ext_vector_type(2)));

__device__ __forceinline__ unsigned short f2bf(float f) {
    union { float f; unsigned u; } v; v.f = f;
    return (unsigned short)((v.u + 0x7fffu + ((v.u >> 16) & 1u)) >> 16);
}

// pack 2 f32 -> 2 bf16 in one dword (low = a, high = b)
__device__ __forceinline__ unsigned cvtpk(float a, float b) {
    unsigned r;
    asm("v_cvt_pk_bf16_f32 %0, %1, %2" : "=v"(r) : "v"(a), "v"(b));
    return r;
}

// prep: x fp32 [B][C][HW] -> xt fp16 [B][HW][C] (transposed), xf bf16 [B][C][HW]
__global__ __launch_bounds__(256) void prep_kernel(
    const float* __restrict__ x1, const float* __restrict__ x2,
    _Float16* __restrict__ x1t, _Float16* __restrict__ x2t,
    unsigned short* __restrict__ x1f, unsigned short* __restrict__ x2f)
{
    __shared__ float lds[32][33];
    int idx = blockIdx.x;            // 0..4095
    int which = idx >> 11;           // 0: x1, 1: x2
    int r = idx & 2047;
    int cb  = r & 3;                 // C/32  = 4
    int hwb = (r >> 2) & 127;        // HW/32 = 128
    int b   = r >> 9;                // 4 batches
    const float* x = which ? x2 : x1;
    _Float16* xt = which ? x2t : x1t;
    unsigned short* xf = which ? x2f : x1f;
    int tid = threadIdx.x;
    int tc = tid >> 5, th = tid & 31;
    #pragma unroll
    for (int k = 0; k < 4; ++k) {
        int cl = tc + 8 * k;
        int c = cb * 32 + cl, hw = hwb * 32 + th;
        float v = x[((size_t)b * CCH + c) * HWSZ + hw];
        lds[cl][th] = v;
        xf[((size_t)b * CCH + c) * HWSZ + hw] = f2bf(v);
    }
    __syncthreads();
    #pragma unroll
    for (int k = 0; k < 4; ++k) {
        int hl = tc + 8 * k;
        xt[((size_t)b * HWSZ + hwb * 32 + hl) * CCH + cb * 32 + th] =
            (_Float16)lds[th][hl];
    }
}

// raw barrier: LDS drain + barrier, no vmcnt drain; sched fences keep the
// staging loads pinned on their issue side.
#define FBAR() do { __builtin_amdgcn_sched_barrier(0); \
    asm volatile("s_waitcnt lgkmcnt(0)" ::: "memory"); \
    __builtin_amdgcn_s_barrier(); \
    __builtin_amdgcn_sched_barrier(0); } while (0)

// Fused partial pass (BOTH softmax passes in one launch), col-tile = 128,
// 16 waves, 48KB LDS, VGPR<=64 -> 2 blocks/CU co-resident (32 waves = HW
// cap): one block's barrier stalls are filled by the other block.
// passSel < 0: grid = 2*128*P, pass = bid>>8. passSel 0/1: grid = 128*P.
// For pass p, col-slice `slice` (128 cols), loop-part `part` (4096/P rows):
//   A[row,col] = sum_c loopT[row][c]*blockT[col][c]   (fp16 MFMA, K=128)
//   E = exp(A) (bf16 -> swizzled LDS)
//   accP[c][col] += sum_row loopF[c][row]*E[row][col] (bf16 MFMA)
//   colsum[col]  += sum_row E
// Schedule per 64-row chunk (R4-proven):
//   issue loads(t+1); gram reads AF(t); E-write; B1; PV reads PA(t)+E;
//   AF<-t+1 (AF readers all pre-B1); B2; PA<-t+1 (PA readers all pre-B2).
__global__ __launch_bounds__(1024, 4) void fused_part(
    const _Float16* __restrict__ x1t, const _Float16* __restrict__ x2t,
    const unsigned short* __restrict__ x1f, const unsigned short* __restrict__ x2f,
    float* __restrict__ accP1, float* __restrict__ cs1,
    float* __restrict__ accP2, float* __restrict__ cs2,
    int P, int passSel)
{
    __shared__ unsigned short AF[8192];   // 64 rows x 128 c fp16, swizzled 16B units
    __shared__ unsigned short PA[8192];   // 128 c x 64 rows bf16, swizzled
    __shared__ unsigned short EB[8192];   // 128 cols x 64 rows bf16, swizzled

    int bid = blockIdx.x;
    int pass, bidp;
    if (passSel < 0) { pass = bid >> 8; bidp = bid & 255; }
    else             { pass = passSel;  bidp = bid; }
    int xcd = bidp & 7, grp = bidp >> 3;  // grp 0..16P-1
    int b = xcd >> 1;                     // 2 XCDs per batch (L2 locality)
    int slice = (grp & 15) + 16 * (xcd & 1);   // 0..31 (128 cols each)
    int part = grp >> 4;                  // 0..P-1
    int tid = threadIdx.x;
    int wave = tid >> 6, lane = tid & 63;
    int l16 = lane & 15, lg = lane >> 4;
    int nt = wave & 3, mh = wave >> 2;    // gram: row-tile nt, col-32-group mh
    int swz = l16 & 7;
    int NC = 64 / P;
    int ch0 = part * NC, ch1 = ch0 + NC;

    const _Float16* loopT  = pass ? x2t : x1t;
    const _Float16* blockT = pass ? x1t : x2t;
    const unsigned short* loopF = pass ? x2f : x1f;
    float* accPo = pass ? accP2 : accP1;
    float* cso   = pass ? cs2   : cs1;

    const _Float16* lT = loopT + (size_t)b * HWSZ * CCH;
    const _Float16* bT = blockT + (size_t)b * HWSZ * CCH;
    const unsigned short* lF = loopF + (size_t)b * CCH * HWSZ;

    // hoist gram B frags: col = slice*128 + mh*32 + tt*16 + l16, K=128
    half8 bfrag[2][4];
    #pragma unroll
    for (int tt = 0; tt < 2; ++tt)
        #pragma unroll
        for (int ks = 0; ks < 4; ++ks)
            bfrag[tt][ks] = *(const half8*)&bT[
                (size_t)(slice * 128 + mh * 32 + tt * 16 + l16) * CCH + ks * 32 + lg * 8];

    // staging addressing: thread owns one 16B unit of each tile.
    // AF: unit u: row=u>>4 (64), s=u&15. LDS unit = row*16 + (s ^ (row&7)).
    int arow = tid >> 4, as_ = tid & 15;
    const _Float16* afsrc = lT + (size_t)arow * CCH + as_ * 8;
    int afw = (arow * 16 + (as_ ^ (arow & 7))) * 8;      // ushort index
    // PA: unit u: c=u>>3 (128), s=u&7
    int pc = tid >> 3, ps = tid & 7;
    const unsigned short* pasrc = lF + (size_t)pc * HWSZ + ps * 8;
    int paw = (pc * 8 + (ps ^ (pc & 7))) * 8;            // ushort index

    float csum0 = 0.f, csum1 = 0.f;
    floatx4 accP[2][2];
    #pragma unroll
    for (int ci = 0; ci < 2; ++ci)
        #pragma unroll
        for (int cj = 0; cj < 2; ++cj) accP[ci][cj] = (floatx4){0.f, 0.f, 0.f, 0.f};

    // E-tile addresses (loop-invariant)
    int wo0 = (mh * 32 + l16) * 64 + (((nt * 2 + (lg >> 1)) ^ swz) << 3) + ((lg & 1) << 2);
    int wo1 = wo0 + 16 * 64;

    // prologue: stage chunk ch0
    {
        floatx4 ga = *(const floatx4*)(afsrc + (size_t)ch0 * 64 * CCH);
        floatx4 gp = *(const floatx4*)(pasrc + ch0 * 64);
        *(floatx4*)&AF[afw] = ga;
        *(floatx4*)&PA[paw] = gp;
    }
    __syncthreads();

    for (int t = ch0; t < ch1; ++t) {
        int t1 = (t + 1 < ch1) ? t + 1 : t;
        // issue next-chunk staging loads (ride over both barriers)
        floatx4 ga = *(const floatx4*)(afsrc + (size_t)t1 * 64 * CCH);
        floatx4 gp = *(const floatx4*)(pasrc + t1 * 64);
        // ---- gram: rows nt*16.., cols mh*32 + {0,16} + l16, K=128 (fp16)
        half8 afr[4];
        #pragma unroll
        for (int ks = 0; ks < 4; ++ks)
            afr[ks] = *(const half8*)&AF[((nt * 16 + l16) * 16 + ((ks * 4 + lg) ^ swz)) * 8];
        floatx4 accA0 = {0.f, 0.f, 0.f, 0.f}, accA1 = {0.f, 0.f, 0.f, 0.f};
        #pragma unroll
        for (int ks = 0; ks < 4; ++ks) {
            accA0 = __builtin_amdgcn_mfma_f32_16x16x32_f16(afr[ks], bfrag[0][ks], accA0, 0, 0, 0);
            accA1 = __builtin_amdgcn_mfma_f32_16x16x32_f16(afr[ks], bfrag[1][ks], accA1, 0, 0, 0);
        }
        // ---- exp (no max-sub: |A| << 88) + pk-bf16 pack + colsum partials
        float v00 = __expf(accA0[0]), v01 = __expf(accA0[1]);
        float v02 = __expf(accA0[2]), v03 = __expf(accA0[3]);
        float v10 = __expf(accA1[0]), v11 = __expf(accA1[1]);
        float v12 = __expf(accA1[2]), v13 = __expf(accA1[3]);
        csum0 += (v00 + v01) + (v02 + v03);
        csum1 += (v10 + v11) + (v12 + v13);
        uint2v e0 = (uint2v){cvtpk(v00, v01), cvtpk(v02, v03)};
        uint2v e1 = (uint2v){cvtpk(v10, v11), cvtpk(v12, v13)};
        *(uint2v*)&EB[wo0] = e0;
        *(uint2v*)&EB[wo1] = e1;
        FBAR();   // B1: E visible; all AF reads of tile t complete block-wide
        // ---- PV: accP[c-tiles nt*2+ci][col-tiles mh*2+cj], k = 64 rows (bf16)
        #pragma unroll
        for (int kf = 0; kf < 2; ++kf) {
            short8 paf[2], ebf[2];
            #pragma unroll
            for (int ci = 0; ci < 2; ++ci) {
                int c = (nt * 2 + ci) * 16 + l16;
                paf[ci] = *(const short8*)&PA[(c * 8 + ((kf * 4 + lg) ^ swz)) * 8];
            }
            #pragma unroll
            for (int cj = 0; cj < 2; ++cj) {
                int ecol = (mh * 2 + cj) * 16 + l16;
                ebf[cj] = *(const short8*)&EB[ecol * 64 + (((kf * 4 + lg) ^ swz) << 3)];
            }
            #pragma unroll
            for (int ci = 0; ci < 2; ++ci)
                #pragma unroll
                for (int cj = 0; cj < 2; ++cj)
                    accP[ci][cj] = __builtin_amdgcn_mfma_f32_16x16x32_bf16(
                        paf[ci], ebf[cj], accP[ci][cj], 0, 0, 0);
        }
        // ---- stage writes: AF (readers finished at B1), then barrier, then PA
        *(floatx4*)&AF[afw] = ga;
        FBAR();   // B2: PV reads of tile t complete; AF(t+1) visible
        *(floatx4*)&PA[paw] = gp;   // visible at next B1
    }
    __syncthreads();   // final PA write drained before aliasing

    // ---- colsum: deterministic cross-wave reduce (alias scratch onto EB)
    float* cspart = (float*)EB;   // [4][128]
    float v = csum0;
    v += __shfl_xor(v, 16, 64); v += __shfl_xor(v, 32, 64);
    float w = csum1;
    w += __shfl_xor(w, 16, 64); w += __shfl_xor(w, 32, 64);
    if (lane < 16) {
        cspart[nt * 128 + mh * 32 + lane] = v;
        cspart[nt * 128 + mh * 32 + 16 + lane] = w;
    }
    __syncthreads();
    size_t sbase = ((size_t)part * BATCH + b) * 32 + slice;
    if (tid < 128)
        cso[sbase * 128 + tid] = cspart[tid] + cspart[128 + tid] +
                                 cspart[256 + tid] + cspart[384 + tid];

    // ---- store partial accP: c = (nt*2+ci)*16 + lg*4 + rr, col = (mh*2+cj)*16 + l16
    float* po = accPo + sbase * (128 * 128);
    #pragma unroll
    for (int ci = 0; ci < 2; ++ci)
        #pragma unroll
        for (int cj = 0; cj < 2; ++cj)
            #pragma unroll
            for (int rr = 0; rr < 4; ++rr)
                po[(size_t)((nt * 2 + ci) * 16 + lg * 4 + rr) * 128 +
                   (mh * 2 + cj) * 16 + l16] = accP[ci][cj][rr];
}

// combine P partials + epilogue: att = accP/colsum;
// out[col] (+)= cw * sum_c gw[c]*sigmoid(att[c][col])*xe[c][col]
template<int ACCUM>
__global__ __launch_bounds__(256) void combine_kernel(
    const float* __restrict__ accPp, const float* __restrict__ csp,
    const float* __restrict__ xe, const float* __restrict__ gw,
    const float* __restrict__ cwp, float* __restrict__ out, int P)
{
    __shared__ float red[256];
    __shared__ float gws[CCH];
    int b = blockIdx.x >> 5, slice = blockIdx.x & 31;
    int tid = threadIdx.x;
    if (tid < CCH) gws[tid] = gw[tid];
    __syncthreads();
    int col = tid & 127, half = tid >> 7;
    float cs = 0.f;
    for (int p = 0; p < P; ++p)
        cs += csp[(((size_t)p * BATCH + b) * 32 + slice) * 128 + col];
    float inv = 1.f / cs;
    float acc = 0.f;
    for (int ci = 0; ci < 64; ++ci) {
        int c = half * 64 + ci;
        float s = 0.f;
        for (int p = 0; p < P; ++p)
            s += accPp[((((size_t)p * BATCH + b) * 32 + slice) * 128 + c) * 128 + col];
        float att = s * inv;
        float mask = 1.f / (1.f + __expf(-att));
        acc += gws[c] * mask * xe[((size_t)b * CCH + c) * HWSZ + slice * 128 + col];
    }
    red[tid] = acc;
    __syncthreads();
    if (tid < 128) {
        float vv = cwp[0] * (red[tid] + red[tid + 128]);
        size_t o = (size_t)b * HWSZ + slice * 128 + tid;
        if (ACCUM) out[o] += vv; else out[o] = vv;
    }
}

extern "C" void kernel_launch(void* const* d_in, const int* in_sizes, int n_in,
                              void* d_out, int out_size, void* d_ws, size_t ws_size,
                              hipStream_t stream) {
    const float* x1 = (const float*)d_in[0];
    const float* x2 = (const float*)d_in[1];
    const float* gw = (const float*)d_in[2];
    const float* cw = (const float*)d_in[3];
    float* out = (float*)d_out;

    char* ws = (char*)d_ws;
    size_t elems = (size_t)BATCH * CCH * HWSZ;  // 2M
    _Float16* x1t = (_Float16*)ws;
    _Float16* x2t = (_Float16*)(ws + elems * 2);
    unsigned short* x1f = (unsigned short*)(ws + elems * 4);
    unsigned short* x2f = (unsigned short*)(ws + elems * 6);
    char* pbase = ws + elems * 8;               // 16 MB used by prep arrays

    // partials per pass: accP P*B*32*128*128*4 + cs P*B*32*128*4
    auto region = [](int P) {
        return (size_t)P * BATCH * 32 * 128 * 128 * 4 +
               (size_t)P * BATCH * 32 * 128 * 4;
    };
    size_t avail = (ws_size > elems * 8) ? ws_size - elems * 8 : 0;
    int P; bool dual;
    if      (avail >= 2 * region(2)) { P = 2; dual = true;  }
    else if (avail >=     region(2)) { P = 2; dual = false; }
    else                             { P = 1; dual = false; }

    size_t accPbytes = (size_t)P * BATCH * 32 * 128 * 128 * 4;
    float* accP1 = (float*)pbase;
    float* cs1   = (float*)(pbase + accPbytes);
    float* accP2 = dual ? (float*)(pbase + region(P)) : accP1;
    float* cs2   = dual ? (float*)(pbase + region(P) + accPbytes) : cs1;

    prep_kernel<<<4096, 256, 0, stream>>>(x1, x2, x1t, x2t, x1f, x2f);

    if (dual) {
        // BOTH passes in one launch: 2 blocks/CU co-resident.
        fused_part<<<2 * 128 * P, 1024, 0, stream>>>(
            x1t, x2t, x1f, x2f, accP1, cs1, accP2, cs2, P, -1);
        combine_kernel<0><<<BATCH * 32, 256, 0, stream>>>(accP1, cs1, x2, gw, cw, out, P);
        combine_kernel<1><<<BATCH * 32, 256, 0, stream>>>(accP2, cs2, x1, gw, cw, out, P);
    } else {
        fused_part<<<128 * P, 1024, 0, stream>>>(
            x1t, x2t, x1f, x2f, accP1, cs1, accP1, cs1, P, 0);
        combine_kernel<0><<<BATCH * 32, 256, 0, stream>>>(accP1, cs1, x2, gw, cw, out, P);
        fused_part<<<128 * P, 1024, 0, stream>>>(
            x1t, x2t, x1f, x2f, accP1, cs1, accP1, cs1, P, 1);
        combine_kernel<1><<<BATCH * 32, 256, 0, stream>>>(accP1, cs1, x1, gw, cw, out, P);
    }
}

// Round 8
// 105.254 us; speedup vs baseline: 4.1144x; 1.7126x over previous
//
#include <hip/hip_runtime.h>
#include <hip/hip_fp16.h>

// Problem constants (B=4, C=128, H=W=64 -> HW=4096)
#define BATCH 4
#define CCH   128
#define HWSZ  4096

typedef _Float16 half8 __attribute__((ext_vector_type(8)));
typedef short short8 __attribute__((ext_vector_type(8)));
typedef float floatx4 __attribute__((ext_vector_type(4)));
typedef unsigned short ushort4v __attribute__((ext_vector_type(4)));
typedef unsigned int uint2v __attribute__((ext_vector_type(2)));

__device__ __forceinline__ unsigned short f2bf(float f) {
    union { float f; unsigned u; } v; v.f = f;
    return (unsigned short)((v.u + 0x7fffu + ((v.u >> 16) & 1u)) >> 16);
}

// pack 2 f32 -> 2 bf16 in one dword (low = a, high = b)
__device__ __forceinline__ unsigned cvtpk(float a, float b) {
    unsigned r;
    asm("v_cvt_pk_bf16_f32 %0, %1, %2" : "=v"(r) : "v"(a), "v"(b));
    return r;
}

// prep: x fp32 [B][C][HW] -> xt fp16 [B][HW][C] (transposed), xf bf16 [B][C][HW]
__global__ __launch_bounds__(256) void prep_kernel(
    const float* __restrict__ x1, const float* __restrict__ x2,
    _Float16* __restrict__ x1t, _Float16* __restrict__ x2t,
    unsigned short* __restrict__ x1f, unsigned short* __restrict__ x2f)
{
    __shared__ float lds[32][33];
    int idx = blockIdx.x;            // 0..4095
    int which = idx >> 11;           // 0: x1, 1: x2
    int r = idx & 2047;
    int cb  = r & 3;                 // C/32  = 4
    int hwb = (r >> 2) & 127;        // HW/32 = 128
    int b   = r >> 9;                // 4 batches
    const float* x = which ? x2 : x1;
    _Float16* xt = which ? x2t : x1t;
    unsigned short* xf = which ? x2f : x1f;
    int tid = threadIdx.x;
    int tc = tid >> 5, th = tid & 31;
    #pragma unroll
    for (int k = 0; k < 4; ++k) {
        int cl = tc + 8 * k;
        int c = cb * 32 + cl, hw = hwb * 32 + th;
        float v = x[((size_t)b * CCH + c) * HWSZ + hw];
        lds[cl][th] = v;
        xf[((size_t)b * CCH + c) * HWSZ + hw] = f2bf(v);
    }
    __syncthreads();
    #pragma unroll
    for (int k = 0; k < 4; ++k) {
        int hl = tc + 8 * k;
        xt[((size_t)b * HWSZ + hwb * 32 + hl) * CCH + cb * 32 + th] =
            (_Float16)lds[th][hl];
    }
}

// raw barrier: LDS drain + barrier, no vmcnt drain; sched fences keep the
// staging loads pinned on their issue side.
#define FBAR() do { __builtin_amdgcn_sched_barrier(0); \
    asm volatile("s_waitcnt lgkmcnt(0)" ::: "memory"); \
    __builtin_amdgcn_s_barrier(); \
    __builtin_amdgcn_sched_barrier(0); } while (0)

// Fused partial pass (BOTH softmax passes in one launch), col-tile = 128,
// 16 waves, 48KB LDS, VGPR<=64 -> 2 blocks/CU co-resident.
// (Unchanged from R7 — proven at 89.5us, ~LDS-BW-limited.)
__global__ __launch_bounds__(1024, 4) void fused_part(
    const _Float16* __restrict__ x1t, const _Float16* __restrict__ x2t,
    const unsigned short* __restrict__ x1f, const unsigned short* __restrict__ x2f,
    float* __restrict__ accP1, float* __restrict__ cs1,
    float* __restrict__ accP2, float* __restrict__ cs2,
    int P, int passSel)
{
    __shared__ unsigned short AF[8192];   // 64 rows x 128 c fp16, swizzled 16B units
    __shared__ unsigned short PA[8192];   // 128 c x 64 rows bf16, swizzled
    __shared__ unsigned short EB[8192];   // 128 cols x 64 rows bf16, swizzled

    int bid = blockIdx.x;
    int pass, bidp;
    if (passSel < 0) { pass = bid >> 8; bidp = bid & 255; }
    else             { pass = passSel;  bidp = bid; }
    int xcd = bidp & 7, grp = bidp >> 3;  // grp 0..16P-1
    int b = xcd >> 1;                     // 2 XCDs per batch (L2 locality)
    int slice = (grp & 15) + 16 * (xcd & 1);   // 0..31 (128 cols each)
    int part = grp >> 4;                  // 0..P-1
    int tid = threadIdx.x;
    int wave = tid >> 6, lane = tid & 63;
    int l16 = lane & 15, lg = lane >> 4;
    int nt = wave & 3, mh = wave >> 2;    // gram: row-tile nt, col-32-group mh
    int swz = l16 & 7;
    int NC = 64 / P;
    int ch0 = part * NC, ch1 = ch0 + NC;

    const _Float16* loopT  = pass ? x2t : x1t;
    const _Float16* blockT = pass ? x1t : x2t;
    const unsigned short* loopF = pass ? x2f : x1f;
    float* accPo = pass ? accP2 : accP1;
    float* cso   = pass ? cs2   : cs1;

    const _Float16* lT = loopT + (size_t)b * HWSZ * CCH;
    const _Float16* bT = blockT + (size_t)b * HWSZ * CCH;
    const unsigned short* lF = loopF + (size_t)b * CCH * HWSZ;

    // hoist gram B frags: col = slice*128 + mh*32 + tt*16 + l16, K=128
    half8 bfrag[2][4];
    #pragma unroll
    for (int tt = 0; tt < 2; ++tt)
        #pragma unroll
        for (int ks = 0; ks < 4; ++ks)
            bfrag[tt][ks] = *(const half8*)&bT[
                (size_t)(slice * 128 + mh * 32 + tt * 16 + l16) * CCH + ks * 32 + lg * 8];

    // staging addressing: thread owns one 16B unit of each tile.
    int arow = tid >> 4, as_ = tid & 15;
    const _Float16* afsrc = lT + (size_t)arow * CCH + as_ * 8;
    int afw = (arow * 16 + (as_ ^ (arow & 7))) * 8;      // ushort index
    int pc = tid >> 3, ps = tid & 7;
    const unsigned short* pasrc = lF + (size_t)pc * HWSZ + ps * 8;
    int paw = (pc * 8 + (ps ^ (pc & 7))) * 8;            // ushort index

    float csum0 = 0.f, csum1 = 0.f;
    floatx4 accP[2][2];
    #pragma unroll
    for (int ci = 0; ci < 2; ++ci)
        #pragma unroll
        for (int cj = 0; cj < 2; ++cj) accP[ci][cj] = (floatx4){0.f, 0.f, 0.f, 0.f};

    // E-tile addresses (loop-invariant)
    int wo0 = (mh * 32 + l16) * 64 + (((nt * 2 + (lg >> 1)) ^ swz) << 3) + ((lg & 1) << 2);
    int wo1 = wo0 + 16 * 64;

    // prologue: stage chunk ch0
    {
        floatx4 ga = *(const floatx4*)(afsrc + (size_t)ch0 * 64 * CCH);
        floatx4 gp = *(const floatx4*)(pasrc + ch0 * 64);
        *(floatx4*)&AF[afw] = ga;
        *(floatx4*)&PA[paw] = gp;
    }
    __syncthreads();

    for (int t = ch0; t < ch1; ++t) {
        int t1 = (t + 1 < ch1) ? t + 1 : t;
        // issue next-chunk staging loads (ride over both barriers)
        floatx4 ga = *(const floatx4*)(afsrc + (size_t)t1 * 64 * CCH);
        floatx4 gp = *(const floatx4*)(pasrc + t1 * 64);
        // ---- gram: rows nt*16.., cols mh*32 + {0,16} + l16, K=128 (fp16)
        half8 afr[4];
        #pragma unroll
        for (int ks = 0; ks < 4; ++ks)
            afr[ks] = *(const half8*)&AF[((nt * 16 + l16) * 16 + ((ks * 4 + lg) ^ swz)) * 8];
        floatx4 accA0 = {0.f, 0.f, 0.f, 0.f}, accA1 = {0.f, 0.f, 0.f, 0.f};
        #pragma unroll
        for (int ks = 0; ks < 4; ++ks) {
            accA0 = __builtin_amdgcn_mfma_f32_16x16x32_f16(afr[ks], bfrag[0][ks], accA0, 0, 0, 0);
            accA1 = __builtin_amdgcn_mfma_f32_16x16x32_f16(afr[ks], bfrag[1][ks], accA1, 0, 0, 0);
        }
        // ---- exp (no max-sub: |A| << 88) + pk-bf16 pack + colsum partials
        float v00 = __expf(accA0[0]), v01 = __expf(accA0[1]);
        float v02 = __expf(accA0[2]), v03 = __expf(accA0[3]);
        float v10 = __expf(accA1[0]), v11 = __expf(accA1[1]);
        float v12 = __expf(accA1[2]), v13 = __expf(accA1[3]);
        csum0 += (v00 + v01) + (v02 + v03);
        csum1 += (v10 + v11) + (v12 + v13);
        uint2v e0 = (uint2v){cvtpk(v00, v01), cvtpk(v02, v03)};
        uint2v e1 = (uint2v){cvtpk(v10, v11), cvtpk(v12, v13)};
        *(uint2v*)&EB[wo0] = e0;
        *(uint2v*)&EB[wo1] = e1;
        FBAR();   // B1: E visible; all AF reads of tile t complete block-wide
        // ---- PV: accP[c-tiles nt*2+ci][col-tiles mh*2+cj], k = 64 rows (bf16)
        #pragma unroll
        for (int kf = 0; kf < 2; ++kf) {
            short8 paf[2], ebf[2];
            #pragma unroll
            for (int ci = 0; ci < 2; ++ci) {
                int c = (nt * 2 + ci) * 16 + l16;
                paf[ci] = *(const short8*)&PA[(c * 8 + ((kf * 4 + lg) ^ swz)) * 8];
            }
            #pragma unroll
            for (int cj = 0; cj < 2; ++cj) {
                int ecol = (mh * 2 + cj) * 16 + l16;
                ebf[cj] = *(const short8*)&EB[ecol * 64 + (((kf * 4 + lg) ^ swz) << 3)];
            }
            #pragma unroll
            for (int ci = 0; ci < 2; ++ci)
                #pragma unroll
                for (int cj = 0; cj < 2; ++cj)
                    accP[ci][cj] = __builtin_amdgcn_mfma_f32_16x16x32_bf16(
                        paf[ci], ebf[cj], accP[ci][cj], 0, 0, 0);
        }
        // ---- stage writes: AF (readers finished at B1), then barrier, then PA
        *(floatx4*)&AF[afw] = ga;
        FBAR();   // B2: PV reads of tile t complete; AF(t+1) visible
        *(floatx4*)&PA[paw] = gp;   // visible at next B1
    }
    __syncthreads();   // final PA write drained before aliasing

    // ---- colsum: deterministic cross-wave reduce (alias scratch onto EB)
    float* cspart = (float*)EB;   // [4][128]
    float v = csum0;
    v += __shfl_xor(v, 16, 64); v += __shfl_xor(v, 32, 64);
    float w = csum1;
    w += __shfl_xor(w, 16, 64); w += __shfl_xor(w, 32, 64);
    if (lane < 16) {
        cspart[nt * 128 + mh * 32 + lane] = v;
        cspart[nt * 128 + mh * 32 + 16 + lane] = w;
    }
    __syncthreads();
    size_t sbase = ((size_t)part * BATCH + b) * 32 + slice;
    if (tid < 128)
        cso[sbase * 128 + tid] = cspart[tid] + cspart[128 + tid] +
                                 cspart[256 + tid] + cspart[384 + tid];

    // ---- store partial accP: c = (nt*2+ci)*16 + lg*4 + rr, col = (mh*2+cj)*16 + l16
    float* po = accPo + sbase * (128 * 128);
    #pragma unroll
    for (int ci = 0; ci < 2; ++ci)
        #pragma unroll
        for (int cj = 0; cj < 2; ++cj)
            #pragma unroll
            for (int rr = 0; rr < 4; ++rr)
                po[(size_t)((nt * 2 + ci) * 16 + lg * 4 + rr) * 128 +
                   (mh * 2 + cj) * 16 + l16] = accP[ci][cj][rr];
}

// merged epilogue: one block per (b, 64-col strip); computes BOTH passes'
// contributions and writes out once (no accumulation ordering, no race).
// out[col] = cw * sum_c gw[c]*( sig(accP1/cs1)*x2[c][col] + sig(accP2/cs2)*x1[c][col] )
__global__ __launch_bounds__(512) void combine2_kernel(
    const float* __restrict__ accP1, const float* __restrict__ cs1,
    const float* __restrict__ accP2, const float* __restrict__ cs2,
    const float* __restrict__ x1, const float* __restrict__ x2,
    const float* __restrict__ gw, const float* __restrict__ cwp,
    float* __restrict__ out, int P)
{
    __shared__ float red[512];
    __shared__ float gws[CCH];
    int b = blockIdx.x >> 6, s2 = blockIdx.x & 63;   // 64-col strip
    int tid = threadIdx.x;
    if (tid < CCH) gws[tid] = gw[tid];
    __syncthreads();
    int c64 = tid & 63, cg = tid >> 6;    // 8 c-groups x 16 c
    int slice = s2 >> 1;
    int colin = (s2 & 1) * 64 + c64;      // col within 128-col slice
    int colg  = s2 * 64 + c64;            // global col
    float d1 = 0.f, d2 = 0.f;
    for (int p = 0; p < P; ++p) {
        size_t sb = (((size_t)p * BATCH + b) * 32 + slice) * 128;
        d1 += cs1[sb + colin];
        d2 += cs2[sb + colin];
    }
    float inv1 = 1.f / d1, inv2 = 1.f / d2;
    float acc = 0.f;
    #pragma unroll 4
    for (int ci = 0; ci < 16; ++ci) {
        int c = cg * 16 + ci;
        size_t fo = (size_t)c * 128 + colin;
        float s1 = 0.f, s2v = 0.f;
        for (int p = 0; p < P; ++p) {
            size_t sb = ((((size_t)p * BATCH + b) * 32 + slice) * (size_t)128) * 128;
            s1  += accP1[sb + fo];
            s2v += accP2[sb + fo];
        }
        float a1 = s1 * inv1, a2 = s2v * inv2;
        float m1 = 1.f / (1.f + __expf(-a1));
        float m2 = 1.f / (1.f + __expf(-a2));
        size_t xei = ((size_t)b * CCH + c) * HWSZ + colg;
        acc += gws[c] * (m1 * x2[xei] + m2 * x1[xei]);
    }
    red[tid] = acc;
    __syncthreads();
    if (tid < 64) {
        float t = 0.f;
        #pragma unroll
        for (int g = 0; g < 8; ++g) t += red[tid + 64 * g];
        out[(size_t)b * HWSZ + s2 * 64 + tid] = cwp[0] * t;
    }
}

// single-pass combine (fallback when workspace can't hold both passes)
template<int ACCUM>
__global__ __launch_bounds__(256) void combine_kernel(
    const float* __restrict__ accPp, const float* __restrict__ csp,
    const float* __restrict__ xe, const float* __restrict__ gw,
    const float* __restrict__ cwp, float* __restrict__ out, int P)
{
    __shared__ float red[256];
    __shared__ float gws[CCH];
    int b = blockIdx.x >> 5, slice = blockIdx.x & 31;
    int tid = threadIdx.x;
    if (tid < CCH) gws[tid] = gw[tid];
    __syncthreads();
    int col = tid & 127, half = tid >> 7;
    float cs = 0.f;
    for (int p = 0; p < P; ++p)
        cs += csp[(((size_t)p * BATCH + b) * 32 + slice) * 128 + col];
    float inv = 1.f / cs;
    float acc = 0.f;
    for (int ci = 0; ci < 64; ++ci) {
        int c = half * 64 + ci;
        float s = 0.f;
        for (int p = 0; p < P; ++p)
            s += accPp[((((size_t)p * BATCH + b) * 32 + slice) * 128 + c) * 128 + col];
        float att = s * inv;
        float mask = 1.f / (1.f + __expf(-att));
        acc += gws[c] * mask * xe[((size_t)b * CCH + c) * HWSZ + slice * 128 + col];
    }
    red[tid] = acc;
    __syncthreads();
    if (tid < 128) {
        float vv = cwp[0] * (red[tid] + red[tid + 128]);
        size_t o = (size_t)b * HWSZ + slice * 128 + tid;
        if (ACCUM) out[o] += vv; else out[o] = vv;
    }
}

extern "C" void kernel_launch(void* const* d_in, const int* in_sizes, int n_in,
                              void* d_out, int out_size, void* d_ws, size_t ws_size,
                              hipStream_t stream) {
    const float* x1 = (const float*)d_in[0];
    const float* x2 = (const float*)d_in[1];
    const float* gw = (const float*)d_in[2];
    const float* cw = (const float*)d_in[3];
    float* out = (float*)d_out;

    char* ws = (char*)d_ws;
    size_t elems = (size_t)BATCH * CCH * HWSZ;  // 2M
    _Float16* x1t = (_Float16*)ws;
    _Float16* x2t = (_Float16*)(ws + elems * 2);
    unsigned short* x1f = (unsigned short*)(ws + elems * 4);
    unsigned short* x2f = (unsigned short*)(ws + elems * 6);
    char* pbase = ws + elems * 8;               // 16 MB used by prep arrays

    // partials per pass: accP P*B*32*128*128*4 + cs P*B*32*128*4
    auto region = [](int P) {
        return (size_t)P * BATCH * 32 * 128 * 128 * 4 +
               (size_t)P * BATCH * 32 * 128 * 4;
    };
    size_t avail = (ws_size > elems * 8) ? ws_size - elems * 8 : 0;
    int P; bool dual;
    if      (avail >= 2 * region(2)) { P = 2; dual = true;  }
    else if (avail >=     region(2)) { P = 2; dual = false; }
    else                             { P = 1; dual = false; }

    size_t accPbytes = (size_t)P * BATCH * 32 * 128 * 128 * 4;
    float* accP1 = (float*)pbase;
    float* cs1   = (float*)(pbase + accPbytes);
    float* accP2 = dual ? (float*)(pbase + region(P)) : accP1;
    float* cs2   = dual ? (float*)(pbase + region(P) + accPbytes) : cs1;

    prep_kernel<<<4096, 256, 0, stream>>>(x1, x2, x1t, x2t, x1f, x2f);

    if (dual) {
        // BOTH passes in one launch: 2 blocks/CU co-resident.
        fused_part<<<2 * 128 * P, 1024, 0, stream>>>(
            x1t, x2t, x1f, x2f, accP1, cs1, accP2, cs2, P, -1);
        // merged epilogue: one launch, both passes, single write per element.
        combine2_kernel<<<BATCH * 64, 512, 0, stream>>>(
            accP1, cs1, accP2, cs2, x1, x2, gw, cw, out, P);
    } else {
        fused_part<<<128 * P, 1024, 0, stream>>>(
            x1t, x2t, x1f, x2f, accP1, cs1, accP1, cs1, P, 0);
        combine_kernel<0><<<BATCH * 32, 256, 0, stream>>>(accP1, cs1, x2, gw, cw, out, P);
        fused_part<<<128 * P, 1024, 0, stream>>>(
            x1t, x2t, x1f, x2f, accP1, cs1, accP1, cs1, P, 1);
        combine_kernel<1><<<BATCH * 32, 256, 0, stream>>>(accP1, cs1, x1, gw, cw, out, P);
    }
}